// Round 17
// baseline (376.783 us; speedup 1.0000x reference)
//
#include <hip/hip_runtime.h>
#include <math.h>

#define HEADS 4
#define CH 64
#define HC 256   // HEADS*CH

typedef __attribute__((ext_vector_type(8))) short bf16x8;
typedef __attribute__((ext_vector_type(4))) float f32x4;

__device__ __forceinline__ float lrelu(float v) { return v > 0.f ? v : 0.2f * v; }

// fp32 -> bf16 bits, round-to-nearest-even
__device__ __forceinline__ unsigned int f2bf(float f) {
    unsigned int u = __float_as_uint(f);
    u += 0x7fffu + ((u >> 16) & 1u);
    return u >> 16;
}
__device__ __forceinline__ float bf2f(unsigned short u) {
    return __uint_as_float(((unsigned int)u) << 16);
}

__device__ __forceinline__ float4 wave_sum4(float4 v) {
#pragma unroll
    for (int m = 32; m; m >>= 1) {
        v.x += __shfl_xor(v.x, m);
        v.y += __shfl_xor(v.y, m);
        v.z += __shfl_xor(v.z, m);
        v.w += __shfl_xor(v.w, m);
    }
    return v;
}

// ---------------------------------------------------------------------------
// CSR build (XCD-affine count/scatter; round-14 measured best).
__global__ void count_kernel(const int* __restrict__ dst, int E, int N,
                             float scale8, int* __restrict__ deg) {
    int r = blockIdx.x & 7;
    int e = (blockIdx.x >> 3) * blockDim.x + threadIdx.x;
    if (e >= E + N) return;
    int d = (e < E) ? dst[e] : e - E;
    int rr = min(7, (int)((float)d * scale8));
    if (rr == r) atomicAdd(&deg[d], 1);
}

__global__ void scan_blocks(const int* __restrict__ deg,
                            int* __restrict__ off,
                            int* __restrict__ bsum, int N) {
    __shared__ int sh[256];
    int t = threadIdx.x;
    int g = blockIdx.x * 256 + t;
    int v = (g < N) ? deg[g] : 0;
    sh[t] = v;
    __syncthreads();
    for (int d = 1; d < 256; d <<= 1) {
        int x = (t >= d) ? sh[t - d] : 0;
        __syncthreads();
        sh[t] += x;
        __syncthreads();
    }
    if (g < N) off[g] = sh[t] - v;
    if (t == 255) bsum[blockIdx.x] = sh[255];
}

__global__ void scan_bsums(int* __restrict__ bsum, int G,
                           int* __restrict__ total_out) {
    __shared__ int sh[256];
    int t = threadIdx.x;
    int chunk = (G + 255) / 256;
    int lo = t * chunk, hi = min(lo + chunk, G);
    int s = 0;
    for (int i = lo; i < hi; ++i) s += bsum[i];
    sh[t] = s;
    __syncthreads();
    for (int d = 1; d < 256; d <<= 1) {
        int x = (t >= d) ? sh[t - d] : 0;
        __syncthreads();
        sh[t] += x;
        __syncthreads();
    }
    int run = (t > 0) ? sh[t - 1] : 0;
    for (int i = lo; i < hi; ++i) { int v = bsum[i]; bsum[i] = run; run += v; }
    if (t == 255) *total_out = sh[255];
}

__global__ void scan_add(int* __restrict__ off, const int* __restrict__ bsum,
                         int N) {
    int g = blockIdx.x * 256 + threadIdx.x;
    if (g < N) off[g] += bsum[blockIdx.x];
}

__global__ void scatter_kernel(const int* __restrict__ src,
                               const int* __restrict__ dst, int E, int N,
                               float scale8,
                               const int* __restrict__ off,
                               int* __restrict__ cursor,
                               int* __restrict__ csr_src) {
    int r = blockIdx.x & 7;
    int e = (blockIdx.x >> 3) * blockDim.x + threadIdx.x;
    if (e >= E + N) return;
    int s, d;
    if (e < E) { s = src[e]; d = dst[e]; } else { s = d = e - E; }
    int rr = min(7, (int)((float)d * scale8));
    if (rr != r) return;
    int p = atomicAdd(&cursor[d], 1);
    csr_src[off[d] + p] = s;
}

// ---------------------------------------------------------------------------
// ALL weight prep in one launch (see round-16 comment).
__device__ __forceinline__ void prep_blk(int b, int t, const float* W,
                                         const float* a_s, const float* a_d,
                                         unsigned short* Wb, float* ws,
                                         float* wd) {
    if (b < 64) {
        Wb[b * 256 + t] = (unsigned short)f2bf(W[(t >> 2) * HC + (t & 3) * CH + b]);
    } else {
        int idx = (b - 64) * 256 + t;      // 0..511
        int which = idx >= 256;
        int i = which ? idx - 256 : idx;   // i = k*4+h
        int k = i >> 2, h = i & 3;
        const float* av = (which ? a_d : a_s) + h * CH;
        const float* Wr = W + (size_t)k * HC + h * CH;
        float s = 0.f;
        for (int c = 0; c < CH; ++c) s += Wr[c] * av[c];
        (which ? wd : ws)[i] = s;
    }
}

__global__ void prep_all(const float* __restrict__ W1,
                         const float* __restrict__ a1s,
                         const float* __restrict__ a1d,
                         float* __restrict__ ws1, float* __restrict__ wd1,
                         const float* __restrict__ W2,
                         const float* __restrict__ a2s,
                         const float* __restrict__ a2d,
                         unsigned short* __restrict__ Wb2,
                         float* __restrict__ ws2, float* __restrict__ wd2,
                         const float* __restrict__ W3,
                         const float* __restrict__ a3s,
                         const float* __restrict__ a3d,
                         unsigned short* __restrict__ Wb3,
                         float* __restrict__ ws3, float* __restrict__ wd3) {
    int b = blockIdx.x, t = threadIdx.x;
    if (b < 66) {
        prep_blk(b, t, W2, a2s, a2d, Wb2, ws2, wd2);
    } else if (b < 132) {
        prep_blk(b - 66, t, W3, a3s, a3d, Wb3, ws3, wd3);
    } else {
        for (int idx = t; idx < 24; idx += blockDim.x) {
            int which = idx >= 12;
            int i = which ? idx - 12 : idx;
            int k = i >> 2, h = i & 3;
            const float* av = (which ? a1d : a1s) + h * CH;
            const float* Wr = W1 + (size_t)k * HC + h * CH;
            float s = 0.f;
            for (int c = 0; c < CH; ++c) s += Wr[c] * av[c];
            (which ? wd1 : ws1)[i] = s;
        }
    }
}

// ---------------------------------------------------------------------------
// Input-space aggregation (layers 2/3): wave per dst node, lane = k (0..63).
// Per-edge broadcast payload packed into ONE uint4 = {4 x bf16 ex, byte
// offset se*128, pad} -> single ds_read_b128 per edge (was b128+b32; LDS
// pipe is the measured bottleneck, m134 cycle counts). Denominator l stays
// fp32 (accumulated before packing).
__global__ void agg_kernel(const int* __restrict__ off,
                           const int* __restrict__ csr_src,
                           const unsigned short* __restrict__ xp,
                           const float4* __restrict__ asrc4,
                           const float4* __restrict__ adst4,
                           uint2* __restrict__ zb2, int N) {
    __shared__ uint4 epk[4][64];
    int node = (blockIdx.x * blockDim.x + threadIdx.x) >> 6;
    int w = (threadIdx.x >> 6) & 3;
    int lane = threadIdx.x & 63;
    if (node >= N) return;
    int o0 = off[node], o1 = off[node + 1];
    int deg = o1 - o0;
    float4 ad = adst4[node];

    float l0 = 0.f, l1 = 0.f, l2 = 0.f, l3 = 0.f;
    float z0 = 0.f, z1 = 0.f, z2 = 0.f, z3 = 0.f;
    const char* xpb = (const char*)xp + lane * 2;

    for (int base = 0; base < deg; base += 64) {
        int i = base + lane;
        int s = 0;
        float4 ev = make_float4(-INFINITY, -INFINITY, -INFINITY, -INFINITY);
        if (i < deg) {
            s = csr_src[o0 + i];
            float4 as = asrc4[s];
            ev.x = lrelu(as.x + ad.x);
            ev.y = lrelu(as.y + ad.y);
            ev.z = lrelu(as.z + ad.z);
            ev.w = lrelu(as.w + ad.w);
        }
        float4 ex;
        ex.x = __expf(ev.x);   // inactive lanes: exp(-inf) = 0
        ex.y = __expf(ev.y);
        ex.z = __expf(ev.z);
        ex.w = __expf(ev.w);
        float4 ls = wave_sum4(ex);
        l0 += ls.x; l1 += ls.y; l2 += ls.z; l3 += ls.w;
        uint4 pk;
        pk.x = f2bf(ex.x) | (f2bf(ex.y) << 16);
        pk.y = f2bf(ex.z) | (f2bf(ex.w) << 16);
        pk.z = (unsigned)s * 128u;            // byte offset of row s in xp
        pk.w = 0;
        epk[w][lane] = pk;

        int cnt = min(64, deg - base);
#pragma unroll 8
        for (int e = 0; e < cnt; ++e) {
            uint4 p = epk[w][e];
            float w0 = __uint_as_float(p.x << 16);
            float w1 = __uint_as_float(p.x & 0xFFFF0000u);
            float w2 = __uint_as_float(p.y << 16);
            float w3 = __uint_as_float(p.y & 0xFFFF0000u);
            float xk = bf2f(*(const unsigned short*)(xpb + p.z));
            z0 += w0 * xk; z1 += w1 * xk;
            z2 += w2 * xk; z3 += w3 * xk;
        }
    }
    float s0 = 0.25f / l0, s1 = 0.25f / l1, s2 = 0.25f / l2, s3 = 0.25f / l3;
    uint2 zo;
    zo.x = f2bf(z0 * s0) | (f2bf(z1 * s1) << 16);
    zo.y = f2bf(z2 * s2) | (f2bf(z3 * s3) << 16);
    zb2[(size_t)node * CH + lane] = zo;
}

// ---------------------------------------------------------------------------
// MFMA post-aggregation GEMM (layers 2/3). A = zb (bf16 [n][j], j=k*4+h),
// B = Wb (bf16 [c][j]). Layouts m89/m120-verified.
// Layer-2 epilogue folds layer-3 logits; layer 3 folds the final linear.
__global__ void gemm_mfma(const unsigned short* __restrict__ zb,
                          const unsigned short* __restrict__ Wb,
                          const float* __restrict__ bias,
                          const float* __restrict__ residual,
                          const float4* __restrict__ wsn4,
                          const float4* __restrict__ wdn4,
                          float4* __restrict__ asrc4,
                          float4* __restrict__ adst4,
                          const float* __restrict__ lin_w,
                          const float* __restrict__ lin_b,
                          float* __restrict__ out_f32,
                          unsigned short* __restrict__ out_pack,
                          float* __restrict__ out_final, int N) {
    int w = threadIdx.x >> 6;
    int lane = threadIdx.x & 63;
    int quad = lane >> 4, col = lane & 15;
    int nbase = blockIdx.x * 64 + w * 16;

    f32x4 zero4 = {0.f, 0.f, 0.f, 0.f};
    f32x4 acc[4];
#pragma unroll
    for (int t = 0; t < 4; ++t) acc[t] = zero4;

    const unsigned short* arow = zb + (size_t)(nbase + col) * HC + quad * 8;
#pragma unroll
    for (int q = 0; q < 8; ++q) {
        bf16x8 af = *(const bf16x8*)(arow + q * 32);
#pragma unroll
        for (int t = 0; t < 4; ++t) {
            const unsigned short* bp = Wb + (size_t)(t * 16 + col) * HC + q * 32 + quad * 8;
            bf16x8 bfrag = *(const bf16x8*)bp;
            acc[t] = __builtin_amdgcn_mfma_f32_16x16x32_bf16(af, bfrag, acc[t], 0, 0, 0);
        }
    }

    if (!out_final) {
        float vv[4][4];   // [t][r]
#pragma unroll
        for (int t = 0; t < 4; ++t) {
            int c = t * 16 + col;
            float bc = bias[c];
#pragma unroll
            for (int r = 0; r < 4; ++r) {
                int n = nbase + quad * 4 + r;
                float v = acc[t][r] + bc;
                v = v > 0.f ? v : expm1f(v);
                v += residual[(size_t)n * CH + c];
                vv[t][r] = v;
                if (n < N) {
                    out_f32[(size_t)n * CH + c] = v;
                    out_pack[(size_t)n * CH + c] = (unsigned short)f2bf(v);
                }
            }
        }
        float4 wsv[4], wdv[4];
#pragma unroll
        for (int t = 0; t < 4; ++t) { wsv[t] = wsn4[t * 16 + col]; wdv[t] = wdn4[t * 16 + col]; }
#pragma unroll
        for (int r = 0; r < 4; ++r) {
            int n = nbase + quad * 4 + r;
            float4 sa = make_float4(0.f, 0.f, 0.f, 0.f);
            float4 da = make_float4(0.f, 0.f, 0.f, 0.f);
#pragma unroll
            for (int t = 0; t < 4; ++t) {
                float v = vv[t][r];
                sa.x += v * wsv[t].x; sa.y += v * wsv[t].y;
                sa.z += v * wsv[t].z; sa.w += v * wsv[t].w;
                da.x += v * wdv[t].x; da.y += v * wdv[t].y;
                da.z += v * wdv[t].z; da.w += v * wdv[t].w;
            }
#pragma unroll
            for (int m = 8; m; m >>= 1) {
                sa.x += __shfl_xor(sa.x, m); sa.y += __shfl_xor(sa.y, m);
                sa.z += __shfl_xor(sa.z, m); sa.w += __shfl_xor(sa.w, m);
                da.x += __shfl_xor(da.x, m); da.y += __shfl_xor(da.y, m);
                da.z += __shfl_xor(da.z, m); da.w += __shfl_xor(da.w, m);
            }
            if (col == 0 && n < N) { asrc4[n] = sa; adst4[n] = da; }
        }
    } else {
        float lw[4], bb[4];
#pragma unroll
        for (int t = 0; t < 4; ++t) { lw[t] = lin_w[t * 16 + col]; bb[t] = bias[t * 16 + col]; }
#pragma unroll
        for (int r = 0; r < 4; ++r) {
            int n = nbase + quad * 4 + r;
            float ts = 0.f;
#pragma unroll
            for (int t = 0; t < 4; ++t) {
                float v = acc[t][r] + bb[t];
                v = v > 0.f ? v : expm1f(v);
                v += residual[(size_t)n * CH + (t * 16 + col)];
                ts += v * lw[t];
            }
            ts += __shfl_xor(ts, 1);
            ts += __shfl_xor(ts, 2);
            ts += __shfl_xor(ts, 4);
            ts += __shfl_xor(ts, 8);
            if (col == 0 && n < N) out_final[n] = ts + lin_b[0];
        }
    }
}

// ---------------------------------------------------------------------------
// Layer 1 (input dim 3): logits, input-space aggregation, epilogue
__global__ void logits1_kernel(const float* __restrict__ x,
                               const float* __restrict__ ws,
                               const float* __restrict__ wd,
                               float4* __restrict__ asrc4,
                               float4* __restrict__ adst4, int N) {
    int n = blockIdx.x * blockDim.x + threadIdx.x;
    if (n >= N) return;
    float x0 = x[3 * n], x1 = x[3 * n + 1], x2 = x[3 * n + 2];
    float4 s4, d4;
    s4.x = x0 * ws[0] + x1 * ws[4] + x2 * ws[8];
    s4.y = x0 * ws[1] + x1 * ws[5] + x2 * ws[9];
    s4.z = x0 * ws[2] + x1 * ws[6] + x2 * ws[10];
    s4.w = x0 * ws[3] + x1 * ws[7] + x2 * ws[11];
    d4.x = x0 * wd[0] + x1 * wd[4] + x2 * wd[8];
    d4.y = x0 * wd[1] + x1 * wd[5] + x2 * wd[9];
    d4.z = x0 * wd[2] + x1 * wd[6] + x2 * wd[10];
    d4.w = x0 * wd[3] + x1 * wd[7] + x2 * wd[11];
    asrc4[n] = s4;
    adst4[n] = d4;
}

// Layer-1 aggregation: thread per node (avg degree ~17).
__global__ void fused1_kernel(const int* __restrict__ off,
                              const int* __restrict__ csr_src,
                              const float* __restrict__ x,
                              const float4* __restrict__ asrc4,
                              const float4* __restrict__ adst4,
                              float4* __restrict__ zl, int N) {
    int n = blockIdx.x * blockDim.x + threadIdx.x;
    if (n >= N) return;
    int o0 = off[n], o1 = off[n + 1];
    float4 ad = adst4[n];
    float z[12];
#pragma unroll
    for (int j = 0; j < 12; ++j) z[j] = 0.f;
    float l0 = 0.f, l1 = 0.f, l2 = 0.f, l3 = 0.f;

    for (int i = o0; i < o1; ++i) {
        int s = csr_src[i];
        float4 as = asrc4[s];
        float e0 = __expf(lrelu(as.x + ad.x));
        float e1 = __expf(lrelu(as.y + ad.y));
        float e2 = __expf(lrelu(as.z + ad.z));
        float e3 = __expf(lrelu(as.w + ad.w));
        l0 += e0; l1 += e1; l2 += e2; l3 += e3;
        float x0 = x[3 * s], x1 = x[3 * s + 1], x2 = x[3 * s + 2];
        z[0] += e0 * x0; z[1]  += e0 * x1; z[2]  += e0 * x2;
        z[3] += e1 * x0; z[4]  += e1 * x1; z[5]  += e1 * x2;
        z[6] += e2 * x0; z[7]  += e2 * x1; z[8]  += e2 * x2;
        z[9] += e3 * x0; z[10] += e3 * x1; z[11] += e3 * x2;
    }
    zl[(size_t)n * 4 + 0] = make_float4(z[0], z[1], z[2], z[3]);
    zl[(size_t)n * 4 + 1] = make_float4(z[4], z[5], z[6], z[7]);
    zl[(size_t)n * 4 + 2] = make_float4(z[8], z[9], z[10], z[11]);
    zl[(size_t)n * 4 + 3] = make_float4(l0, l1, l2, l3);
}

// Layer-1 epilogue: fp32 out + packed bf16 rows + FOLDED layer-2 logits.
__global__ void epi1_kernel(const float4* __restrict__ zl,
                            const float* __restrict__ W1,
                            const float* __restrict__ b1,
                            const float4* __restrict__ ws2_4,
                            const float4* __restrict__ wd2_4,
                            float4* __restrict__ asrc4,
                            float4* __restrict__ adst4,
                            float* __restrict__ out,
                            unsigned short* __restrict__ out_pack, int N) {
    int node = (blockIdx.x * blockDim.x + threadIdx.x) >> 6;
    int c = threadIdx.x & 63;
    if (node >= N) return;
    float4 z0 = zl[(size_t)node * 4 + 0];
    float4 z1 = zl[(size_t)node * 4 + 1];
    float4 z2 = zl[(size_t)node * 4 + 2];
    float4 l4 = zl[(size_t)node * 4 + 3];
    float i0 = 0.25f / l4.x, i1 = 0.25f / l4.y;
    float i2 = 0.25f / l4.z, i3 = 0.25f / l4.w;
    float acc =
        (z0.x * W1[0 * HC +   0 + c] + z0.y * W1[1 * HC +   0 + c] + z0.z * W1[2 * HC +   0 + c]) * i0 +
        (z0.w * W1[0 * HC +  64 + c] + z1.x * W1[1 * HC +  64 + c] + z1.y * W1[2 * HC +  64 + c]) * i1 +
        (z1.z * W1[0 * HC + 128 + c] + z1.w * W1[1 * HC + 128 + c] + z2.x * W1[2 * HC + 128 + c]) * i2 +
        (z2.y * W1[0 * HC + 192 + c] + z2.z * W1[1 * HC + 192 + c] + z2.w * W1[2 * HC + 192 + c]) * i3;
    float v = acc + b1[c];
    v = v > 0.f ? v : expm1f(v);
    out[(size_t)node * CH + c] = v;
    out_pack[(size_t)node * CH + c] = (unsigned short)f2bf(v);
    float4 wsv = ws2_4[c], wdv = wd2_4[c];
    float4 sacc = make_float4(v * wsv.x, v * wsv.y, v * wsv.z, v * wsv.w);
    float4 dacc = make_float4(v * wdv.x, v * wdv.y, v * wdv.z, v * wdv.w);
    sacc = wave_sum4(sacc);
    dacc = wave_sum4(dacc);
    if (c == 0) { asrc4[node] = sacc; adst4[node] = dacc; }
}

// ---------------------------------------------------------------------------
extern "C" void kernel_launch(void* const* d_in, const int* in_sizes, int n_in,
                              void* d_out, int out_size, void* d_ws, size_t ws_size,
                              hipStream_t stream) {
    const float* x      = (const float*)d_in[0];
    const int*   ei     = (const int*)  d_in[1];
    const float* W1     = (const float*)d_in[2];
    const float* a1s    = (const float*)d_in[3];
    const float* a1d    = (const float*)d_in[4];
    const float* b1     = (const float*)d_in[5];
    const float* W2     = (const float*)d_in[6];
    const float* a2s    = (const float*)d_in[7];
    const float* a2d    = (const float*)d_in[8];
    const float* b2     = (const float*)d_in[9];
    const float* W3     = (const float*)d_in[10];
    const float* a3s    = (const float*)d_in[11];
    const float* a3d    = (const float*)d_in[12];
    const float* b3     = (const float*)d_in[13];
    const float* lin_w  = (const float*)d_in[14];
    const float* lin_b  = (const float*)d_in[15];

    const int N = in_sizes[0] / 3;
    const int E = in_sizes[1] / 2;
    const int Et = E + N;
    const int* src = ei;
    const int* dst = ei + E;
    const float scale8 = 8.0f / (float)N;   // consistent d->range map

    // ---- workspace layout ----
    unsigned short* zb  = (unsigned short*)d_ws;          // N*256 bf16
    unsigned short* xpA = zb  + (size_t)N * HC;           // N*64
    unsigned short* xpB = xpA + (size_t)N * CH;           // N*64
    unsigned short* Wb2 = xpB + (size_t)N * CH;           // 16384
    unsigned short* Wb3 = Wb2 + 16384;                    // 16384
    float* bufA   = (float*)(Wb3 + 16384);                // N*64
    float* bufB   = bufA + (size_t)N * CH;                // N*64
    float* zl     = bufB + (size_t)N * CH;                // N*16
    float* asrc   = zl   + (size_t)N * 16;                // N*4
    float* adst   = asrc + (size_t)N * 4;                 // N*4
    float* ws1    = adst + (size_t)N * 4;                 // 16
    float* wd1    = ws1 + 16;                             // 16
    float* ws2    = wd1 + 16;                             // 256
    float* wd2    = ws2 + 256;                            // 256
    float* ws3    = wd2 + 256;                            // 256
    float* wd3    = ws3 + 256;                            // 256
    int* deg      = (int*)(wd3 + 256);                    // N
    int* cursor   = deg + N;                              // N (adjacent: 1 memset)
    int* off      = cursor + N;                           // N+4
    int* bsum     = off + N + 4;                          // 256
    int* csr_src  = bsum + 256;                           // Et

    const int B = 256;
    const int G = (N + 255) / 256;
    const int EB = (Et + B - 1) / B;

    // ---- CSR build (XCD-affine count/scatter) ----
    hipMemsetAsync(deg, 0, (size_t)2 * N * sizeof(int), stream);  // deg+cursor
    count_kernel<<<EB * 8, B, 0, stream>>>(dst, E, N, scale8, deg);
    scan_blocks<<<G, B, 0, stream>>>(deg, off, bsum, N);
    scan_bsums<<<1, B, 0, stream>>>(bsum, G, off + N);
    scan_add<<<G, B, 0, stream>>>(off, bsum, N);
    scatter_kernel<<<EB * 8, B, 0, stream>>>(src, dst, E, N, scale8,
                                             off, cursor, csr_src);

    // ---- all weight prep in one launch ----
    prep_all<<<133, B, 0, stream>>>(W1, a1s, a1d, ws1, wd1,
                                    W2, a2s, a2d, Wb2, ws2, wd2,
                                    W3, a3s, a3d, Wb3, ws3, wd3);

    int nwave_blocks = (N * 64 + B - 1) / B;   // wave per node
    int ngemm_blocks = (N + 63) / 64;          // 64 nodes per block

    // ---- Layer 1 (input-space aggregation over 3-dim x) ----
    logits1_kernel<<<(N + B - 1) / B, B, 0, stream>>>(
        x, ws1, wd1, (float4*)asrc, (float4*)adst, N);
    fused1_kernel<<<(N + B - 1) / B, B, 0, stream>>>(
        off, csr_src, x, (const float4*)asrc, (const float4*)adst,
        (float4*)zl, N);
    epi1_kernel<<<nwave_blocks, B, 0, stream>>>(
        (const float4*)zl, W1, b1, (const float4*)ws2, (const float4*)wd2,
        (float4*)asrc, (float4*)adst, bufA, xpA, N);

    // ---- Layer 2 (gemm epilogue folds layer-3 logits) ----
    agg_kernel<<<nwave_blocks, B, 0, stream>>>(
        off, csr_src, xpA, (const float4*)asrc, (const float4*)adst,
        (uint2*)zb, N);
    gemm_mfma<<<ngemm_blocks, B, 0, stream>>>(
        zb, Wb2, b2, bufA, (const float4*)ws3, (const float4*)wd3,
        (float4*)asrc, (float4*)adst,
        nullptr, nullptr, bufB, xpB, nullptr, N);

    // ---- Layer 3 (+ fused final linear) ----
    agg_kernel<<<nwave_blocks, B, 0, stream>>>(
        off, csr_src, xpB, (const float4*)asrc, (const float4*)adst,
        (uint2*)zb, N);
    gemm_mfma<<<ngemm_blocks, B, 0, stream>>>(
        zb, Wb3, b3, bufB, nullptr, nullptr, nullptr, nullptr,
        lin_w, lin_b, nullptr, nullptr, (float*)d_out, N);
}

// Round 18
// 349.892 us; speedup vs baseline: 1.0769x; 1.0769x over previous
//
#include <hip/hip_runtime.h>
#include <math.h>

#define HEADS 4
#define CH 64
#define HC 256   // HEADS*CH

typedef __attribute__((ext_vector_type(8))) short bf16x8;
typedef __attribute__((ext_vector_type(4))) float f32x4;

__device__ __forceinline__ float lrelu(float v) { return v > 0.f ? v : 0.2f * v; }

// fp32 -> bf16 bits, round-to-nearest-even
__device__ __forceinline__ unsigned int f2bf(float f) {
    unsigned int u = __float_as_uint(f);
    u += 0x7fffu + ((u >> 16) & 1u);
    return u >> 16;
}
__device__ __forceinline__ float bf2f(unsigned short u) {
    return __uint_as_float(((unsigned int)u) << 16);
}

__device__ __forceinline__ float4 wave_sum4(float4 v) {
#pragma unroll
    for (int m = 32; m; m >>= 1) {
        v.x += __shfl_xor(v.x, m);
        v.y += __shfl_xor(v.y, m);
        v.z += __shfl_xor(v.z, m);
        v.w += __shfl_xor(v.w, m);
    }
    return v;
}

// ---------------------------------------------------------------------------
// CSR build (XCD-affine count/scatter; round-14 measured best).
__global__ void count_kernel(const int* __restrict__ dst, int E, int N,
                             float scale8, int* __restrict__ deg) {
    int r = blockIdx.x & 7;
    int e = (blockIdx.x >> 3) * blockDim.x + threadIdx.x;
    if (e >= E + N) return;
    int d = (e < E) ? dst[e] : e - E;
    int rr = min(7, (int)((float)d * scale8));
    if (rr == r) atomicAdd(&deg[d], 1);
}

__global__ void scan_blocks(const int* __restrict__ deg,
                            int* __restrict__ off,
                            int* __restrict__ bsum, int N) {
    __shared__ int sh[256];
    int t = threadIdx.x;
    int g = blockIdx.x * 256 + t;
    int v = (g < N) ? deg[g] : 0;
    sh[t] = v;
    __syncthreads();
    for (int d = 1; d < 256; d <<= 1) {
        int x = (t >= d) ? sh[t - d] : 0;
        __syncthreads();
        sh[t] += x;
        __syncthreads();
    }
    if (g < N) off[g] = sh[t] - v;
    if (t == 255) bsum[blockIdx.x] = sh[255];
}

__global__ void scan_bsums(int* __restrict__ bsum, int G,
                           int* __restrict__ total_out) {
    __shared__ int sh[256];
    int t = threadIdx.x;
    int chunk = (G + 255) / 256;
    int lo = t * chunk, hi = min(lo + chunk, G);
    int s = 0;
    for (int i = lo; i < hi; ++i) s += bsum[i];
    sh[t] = s;
    __syncthreads();
    for (int d = 1; d < 256; d <<= 1) {
        int x = (t >= d) ? sh[t - d] : 0;
        __syncthreads();
        sh[t] += x;
        __syncthreads();
    }
    int run = (t > 0) ? sh[t - 1] : 0;
    for (int i = lo; i < hi; ++i) { int v = bsum[i]; bsum[i] = run; run += v; }
    if (t == 255) *total_out = sh[255];
}

__global__ void scan_add(int* __restrict__ off, const int* __restrict__ bsum,
                         int N) {
    int g = blockIdx.x * 256 + threadIdx.x;
    if (g < N) off[g] += bsum[blockIdx.x];
}

__global__ void scatter_kernel(const int* __restrict__ src,
                               const int* __restrict__ dst, int E, int N,
                               float scale8,
                               const int* __restrict__ off,
                               int* __restrict__ cursor,
                               int* __restrict__ csr_src) {
    int r = blockIdx.x & 7;
    int e = (blockIdx.x >> 3) * blockDim.x + threadIdx.x;
    if (e >= E + N) return;
    int s, d;
    if (e < E) { s = src[e]; d = dst[e]; } else { s = d = e - E; }
    int rr = min(7, (int)((float)d * scale8));
    if (rr != r) return;
    int p = atomicAdd(&cursor[d], 1);
    csr_src[off[d] + p] = s;
}

// ---------------------------------------------------------------------------
// ALL weight prep in one launch (see round-16 comment).
__device__ __forceinline__ void prep_blk(int b, int t, const float* W,
                                         const float* a_s, const float* a_d,
                                         unsigned short* Wb, float* ws,
                                         float* wd) {
    if (b < 64) {
        Wb[b * 256 + t] = (unsigned short)f2bf(W[(t >> 2) * HC + (t & 3) * CH + b]);
    } else {
        int idx = (b - 64) * 256 + t;      // 0..511
        int which = idx >= 256;
        int i = which ? idx - 256 : idx;   // i = k*4+h
        int k = i >> 2, h = i & 3;
        const float* av = (which ? a_d : a_s) + h * CH;
        const float* Wr = W + (size_t)k * HC + h * CH;
        float s = 0.f;
        for (int c = 0; c < CH; ++c) s += Wr[c] * av[c];
        (which ? wd : ws)[i] = s;
    }
}

__global__ void prep_all(const float* __restrict__ W1,
                         const float* __restrict__ a1s,
                         const float* __restrict__ a1d,
                         float* __restrict__ ws1, float* __restrict__ wd1,
                         const float* __restrict__ W2,
                         const float* __restrict__ a2s,
                         const float* __restrict__ a2d,
                         unsigned short* __restrict__ Wb2,
                         float* __restrict__ ws2, float* __restrict__ wd2,
                         const float* __restrict__ W3,
                         const float* __restrict__ a3s,
                         const float* __restrict__ a3d,
                         unsigned short* __restrict__ Wb3,
                         float* __restrict__ ws3, float* __restrict__ wd3) {
    int b = blockIdx.x, t = threadIdx.x;
    if (b < 66) {
        prep_blk(b, t, W2, a2s, a2d, Wb2, ws2, wd2);
    } else if (b < 132) {
        prep_blk(b - 66, t, W3, a3s, a3d, Wb3, ws3, wd3);
    } else {
        for (int idx = t; idx < 24; idx += blockDim.x) {
            int which = idx >= 12;
            int i = which ? idx - 12 : idx;
            int k = i >> 2, h = i & 3;
            const float* av = (which ? a1d : a1s) + h * CH;
            const float* Wr = W1 + (size_t)k * HC + h * CH;
            float s = 0.f;
            for (int c = 0; c < CH; ++c) s += Wr[c] * av[c];
            (which ? wd1 : ws1)[i] = s;
        }
    }
}

// ---------------------------------------------------------------------------
// Input-space aggregation (layers 2/3): wave per dst node, lane = k (0..63).
// exs: float4 LDS broadcast (no unpack — round-17 showed unpacking costs
// more VALU than the saved ds_read); sss stores PRE-SHIFTED byte offset
// s*128 (one less shift per edge-lane in the hot loop).
__global__ void agg_kernel(const int* __restrict__ off,
                           const int* __restrict__ csr_src,
                           const unsigned short* __restrict__ xp,
                           const float4* __restrict__ asrc4,
                           const float4* __restrict__ adst4,
                           uint2* __restrict__ zb2, int N) {
    __shared__ float4 exs[4][64];
    __shared__ unsigned int sss[4][64];
    int node = (blockIdx.x * blockDim.x + threadIdx.x) >> 6;
    int w = (threadIdx.x >> 6) & 3;
    int lane = threadIdx.x & 63;
    if (node >= N) return;
    int o0 = off[node], o1 = off[node + 1];
    int deg = o1 - o0;
    float4 ad = adst4[node];

    float l0 = 0.f, l1 = 0.f, l2 = 0.f, l3 = 0.f;
    float z0 = 0.f, z1 = 0.f, z2 = 0.f, z3 = 0.f;
    const char* xpb = (const char*)xp + lane * 2;

    for (int base = 0; base < deg; base += 64) {
        int i = base + lane;
        int s = 0;
        float4 ev = make_float4(-INFINITY, -INFINITY, -INFINITY, -INFINITY);
        if (i < deg) {
            s = csr_src[o0 + i];
            float4 as = asrc4[s];
            ev.x = lrelu(as.x + ad.x);
            ev.y = lrelu(as.y + ad.y);
            ev.z = lrelu(as.z + ad.z);
            ev.w = lrelu(as.w + ad.w);
        }
        float4 ex;
        ex.x = __expf(ev.x);   // inactive lanes: exp(-inf) = 0
        ex.y = __expf(ev.y);
        ex.z = __expf(ev.z);
        ex.w = __expf(ev.w);
        float4 ls = wave_sum4(ex);
        l0 += ls.x; l1 += ls.y; l2 += ls.z; l3 += ls.w;
        exs[w][lane] = ex;
        sss[w][lane] = (unsigned)s * 128u;   // byte offset of row s in xp

        int cnt = min(64, deg - base);
#pragma unroll 4
        for (int e = 0; e < cnt; ++e) {
            unsigned soff = sss[w][e];
            float4 exe = exs[w][e];
            float xk = bf2f(*(const unsigned short*)(xpb + soff));
            z0 += exe.x * xk; z1 += exe.y * xk;
            z2 += exe.z * xk; z3 += exe.w * xk;
        }
    }
    float s0 = 0.25f / l0, s1 = 0.25f / l1, s2 = 0.25f / l2, s3 = 0.25f / l3;
    uint2 zo;
    zo.x = f2bf(z0 * s0) | (f2bf(z1 * s1) << 16);
    zo.y = f2bf(z2 * s2) | (f2bf(z3 * s3) << 16);
    zb2[(size_t)node * CH + lane] = zo;
}

// ---------------------------------------------------------------------------
// MFMA post-aggregation GEMM (layers 2/3). A = zb (bf16 [n][j], j=k*4+h),
// B = Wb (bf16 [c][j]). Layouts m89/m120-verified.
// Layer-2 epilogue folds layer-3 logits; layer 3 folds the final linear.
__global__ void gemm_mfma(const unsigned short* __restrict__ zb,
                          const unsigned short* __restrict__ Wb,
                          const float* __restrict__ bias,
                          const float* __restrict__ residual,
                          const float4* __restrict__ wsn4,
                          const float4* __restrict__ wdn4,
                          float4* __restrict__ asrc4,
                          float4* __restrict__ adst4,
                          const float* __restrict__ lin_w,
                          const float* __restrict__ lin_b,
                          float* __restrict__ out_f32,
                          unsigned short* __restrict__ out_pack,
                          float* __restrict__ out_final, int N) {
    int w = threadIdx.x >> 6;
    int lane = threadIdx.x & 63;
    int quad = lane >> 4, col = lane & 15;
    int nbase = blockIdx.x * 64 + w * 16;

    f32x4 zero4 = {0.f, 0.f, 0.f, 0.f};
    f32x4 acc[4];
#pragma unroll
    for (int t = 0; t < 4; ++t) acc[t] = zero4;

    const unsigned short* arow = zb + (size_t)(nbase + col) * HC + quad * 8;
#pragma unroll
    for (int q = 0; q < 8; ++q) {
        bf16x8 af = *(const bf16x8*)(arow + q * 32);
#pragma unroll
        for (int t = 0; t < 4; ++t) {
            const unsigned short* bp = Wb + (size_t)(t * 16 + col) * HC + q * 32 + quad * 8;
            bf16x8 bfrag = *(const bf16x8*)bp;
            acc[t] = __builtin_amdgcn_mfma_f32_16x16x32_bf16(af, bfrag, acc[t], 0, 0, 0);
        }
    }

    if (!out_final) {
        float vv[4][4];   // [t][r]
#pragma unroll
        for (int t = 0; t < 4; ++t) {
            int c = t * 16 + col;
            float bc = bias[c];
#pragma unroll
            for (int r = 0; r < 4; ++r) {
                int n = nbase + quad * 4 + r;
                float v = acc[t][r] + bc;
                v = v > 0.f ? v : expm1f(v);
                v += residual[(size_t)n * CH + c];
                vv[t][r] = v;
                if (n < N) {
                    out_f32[(size_t)n * CH + c] = v;
                    out_pack[(size_t)n * CH + c] = (unsigned short)f2bf(v);
                }
            }
        }
        float4 wsv[4], wdv[4];
#pragma unroll
        for (int t = 0; t < 4; ++t) { wsv[t] = wsn4[t * 16 + col]; wdv[t] = wdn4[t * 16 + col]; }
#pragma unroll
        for (int r = 0; r < 4; ++r) {
            int n = nbase + quad * 4 + r;
            float4 sa = make_float4(0.f, 0.f, 0.f, 0.f);
            float4 da = make_float4(0.f, 0.f, 0.f, 0.f);
#pragma unroll
            for (int t = 0; t < 4; ++t) {
                float v = vv[t][r];
                sa.x += v * wsv[t].x; sa.y += v * wsv[t].y;
                sa.z += v * wsv[t].z; sa.w += v * wsv[t].w;
                da.x += v * wdv[t].x; da.y += v * wdv[t].y;
                da.z += v * wdv[t].z; da.w += v * wdv[t].w;
            }
#pragma unroll
            for (int m = 8; m; m >>= 1) {
                sa.x += __shfl_xor(sa.x, m); sa.y += __shfl_xor(sa.y, m);
                sa.z += __shfl_xor(sa.z, m); sa.w += __shfl_xor(sa.w, m);
                da.x += __shfl_xor(da.x, m); da.y += __shfl_xor(da.y, m);
                da.z += __shfl_xor(da.z, m); da.w += __shfl_xor(da.w, m);
            }
            if (col == 0 && n < N) { asrc4[n] = sa; adst4[n] = da; }
        }
    } else {
        float lw[4], bb[4];
#pragma unroll
        for (int t = 0; t < 4; ++t) { lw[t] = lin_w[t * 16 + col]; bb[t] = bias[t * 16 + col]; }
#pragma unroll
        for (int r = 0; r < 4; ++r) {
            int n = nbase + quad * 4 + r;
            float ts = 0.f;
#pragma unroll
            for (int t = 0; t < 4; ++t) {
                float v = acc[t][r] + bb[t];
                v = v > 0.f ? v : expm1f(v);
                v += residual[(size_t)n * CH + (t * 16 + col)];
                ts += v * lw[t];
            }
            ts += __shfl_xor(ts, 1);
            ts += __shfl_xor(ts, 2);
            ts += __shfl_xor(ts, 4);
            ts += __shfl_xor(ts, 8);
            if (col == 0 && n < N) out_final[n] = ts + lin_b[0];
        }
    }
}

// ---------------------------------------------------------------------------
// Layer 1 (input dim 3): logits, input-space aggregation, epilogue
__global__ void logits1_kernel(const float* __restrict__ x,
                               const float* __restrict__ ws,
                               const float* __restrict__ wd,
                               float4* __restrict__ asrc4,
                               float4* __restrict__ adst4, int N) {
    int n = blockIdx.x * blockDim.x + threadIdx.x;
    if (n >= N) return;
    float x0 = x[3 * n], x1 = x[3 * n + 1], x2 = x[3 * n + 2];
    float4 s4, d4;
    s4.x = x0 * ws[0] + x1 * ws[4] + x2 * ws[8];
    s4.y = x0 * ws[1] + x1 * ws[5] + x2 * ws[9];
    s4.z = x0 * ws[2] + x1 * ws[6] + x2 * ws[10];
    s4.w = x0 * ws[3] + x1 * ws[7] + x2 * ws[11];
    d4.x = x0 * wd[0] + x1 * wd[4] + x2 * wd[8];
    d4.y = x0 * wd[1] + x1 * wd[5] + x2 * wd[9];
    d4.z = x0 * wd[2] + x1 * wd[6] + x2 * wd[10];
    d4.w = x0 * wd[3] + x1 * wd[7] + x2 * wd[11];
    asrc4[n] = s4;
    adst4[n] = d4;
}

// Layer-1 aggregation: thread per node (avg degree ~17).
__global__ void fused1_kernel(const int* __restrict__ off,
                              const int* __restrict__ csr_src,
                              const float* __restrict__ x,
                              const float4* __restrict__ asrc4,
                              const float4* __restrict__ adst4,
                              float4* __restrict__ zl, int N) {
    int n = blockIdx.x * blockDim.x + threadIdx.x;
    if (n >= N) return;
    int o0 = off[n], o1 = off[n + 1];
    float4 ad = adst4[n];
    float z[12];
#pragma unroll
    for (int j = 0; j < 12; ++j) z[j] = 0.f;
    float l0 = 0.f, l1 = 0.f, l2 = 0.f, l3 = 0.f;

    for (int i = o0; i < o1; ++i) {
        int s = csr_src[i];
        float4 as = asrc4[s];
        float e0 = __expf(lrelu(as.x + ad.x));
        float e1 = __expf(lrelu(as.y + ad.y));
        float e2 = __expf(lrelu(as.z + ad.z));
        float e3 = __expf(lrelu(as.w + ad.w));
        l0 += e0; l1 += e1; l2 += e2; l3 += e3;
        float x0 = x[3 * s], x1 = x[3 * s + 1], x2 = x[3 * s + 2];
        z[0] += e0 * x0; z[1]  += e0 * x1; z[2]  += e0 * x2;
        z[3] += e1 * x0; z[4]  += e1 * x1; z[5]  += e1 * x2;
        z[6] += e2 * x0; z[7]  += e2 * x1; z[8]  += e2 * x2;
        z[9] += e3 * x0; z[10] += e3 * x1; z[11] += e3 * x2;
    }
    zl[(size_t)n * 4 + 0] = make_float4(z[0], z[1], z[2], z[3]);
    zl[(size_t)n * 4 + 1] = make_float4(z[4], z[5], z[6], z[7]);
    zl[(size_t)n * 4 + 2] = make_float4(z[8], z[9], z[10], z[11]);
    zl[(size_t)n * 4 + 3] = make_float4(l0, l1, l2, l3);
}

// Layer-1 epilogue: fp32 out + packed bf16 rows + FOLDED layer-2 logits.
__global__ void epi1_kernel(const float4* __restrict__ zl,
                            const float* __restrict__ W1,
                            const float* __restrict__ b1,
                            const float4* __restrict__ ws2_4,
                            const float4* __restrict__ wd2_4,
                            float4* __restrict__ asrc4,
                            float4* __restrict__ adst4,
                            float* __restrict__ out,
                            unsigned short* __restrict__ out_pack, int N) {
    int node = (blockIdx.x * blockDim.x + threadIdx.x) >> 6;
    int c = threadIdx.x & 63;
    if (node >= N) return;
    float4 z0 = zl[(size_t)node * 4 + 0];
    float4 z1 = zl[(size_t)node * 4 + 1];
    float4 z2 = zl[(size_t)node * 4 + 2];
    float4 l4 = zl[(size_t)node * 4 + 3];
    float i0 = 0.25f / l4.x, i1 = 0.25f / l4.y;
    float i2 = 0.25f / l4.z, i3 = 0.25f / l4.w;
    float acc =
        (z0.x * W1[0 * HC +   0 + c] + z0.y * W1[1 * HC +   0 + c] + z0.z * W1[2 * HC +   0 + c]) * i0 +
        (z0.w * W1[0 * HC +  64 + c] + z1.x * W1[1 * HC +  64 + c] + z1.y * W1[2 * HC +  64 + c]) * i1 +
        (z1.z * W1[0 * HC + 128 + c] + z1.w * W1[1 * HC + 128 + c] + z2.x * W1[2 * HC + 128 + c]) * i2 +
        (z2.y * W1[0 * HC + 192 + c] + z2.z * W1[1 * HC + 192 + c] + z2.w * W1[2 * HC + 192 + c]) * i3;
    float v = acc + b1[c];
    v = v > 0.f ? v : expm1f(v);
    out[(size_t)node * CH + c] = v;
    out_pack[(size_t)node * CH + c] = (unsigned short)f2bf(v);
    float4 wsv = ws2_4[c], wdv = wd2_4[c];
    float4 sacc = make_float4(v * wsv.x, v * wsv.y, v * wsv.z, v * wsv.w);
    float4 dacc = make_float4(v * wdv.x, v * wdv.y, v * wdv.z, v * wdv.w);
    sacc = wave_sum4(sacc);
    dacc = wave_sum4(dacc);
    if (c == 0) { asrc4[node] = sacc; adst4[node] = dacc; }
}

// ---------------------------------------------------------------------------
extern "C" void kernel_launch(void* const* d_in, const int* in_sizes, int n_in,
                              void* d_out, int out_size, void* d_ws, size_t ws_size,
                              hipStream_t stream) {
    const float* x      = (const float*)d_in[0];
    const int*   ei     = (const int*)  d_in[1];
    const float* W1     = (const float*)d_in[2];
    const float* a1s    = (const float*)d_in[3];
    const float* a1d    = (const float*)d_in[4];
    const float* b1     = (const float*)d_in[5];
    const float* W2     = (const float*)d_in[6];
    const float* a2s    = (const float*)d_in[7];
    const float* a2d    = (const float*)d_in[8];
    const float* b2     = (const float*)d_in[9];
    const float* W3     = (const float*)d_in[10];
    const float* a3s    = (const float*)d_in[11];
    const float* a3d    = (const float*)d_in[12];
    const float* b3     = (const float*)d_in[13];
    const float* lin_w  = (const float*)d_in[14];
    const float* lin_b  = (const float*)d_in[15];

    const int N = in_sizes[0] / 3;
    const int E = in_sizes[1] / 2;
    const int Et = E + N;
    const int* src = ei;
    const int* dst = ei + E;
    const float scale8 = 8.0f / (float)N;   // consistent d->range map

    // ---- workspace layout ----
    unsigned short* zb  = (unsigned short*)d_ws;          // N*256 bf16
    unsigned short* xpA = zb  + (size_t)N * HC;           // N*64
    unsigned short* xpB = xpA + (size_t)N * CH;           // N*64
    unsigned short* Wb2 = xpB + (size_t)N * CH;           // 16384
    unsigned short* Wb3 = Wb2 + 16384;                    // 16384
    float* bufA   = (float*)(Wb3 + 16384);                // N*64
    float* bufB   = bufA + (size_t)N * CH;                // N*64
    float* zl     = bufB + (size_t)N * CH;                // N*16
    float* asrc   = zl   + (size_t)N * 16;                // N*4
    float* adst   = asrc + (size_t)N * 4;                 // N*4
    float* ws1    = adst + (size_t)N * 4;                 // 16
    float* wd1    = ws1 + 16;                             // 16
    float* ws2    = wd1 + 16;                             // 256
    float* wd2    = ws2 + 256;                            // 256
    float* ws3    = wd2 + 256;                            // 256
    float* wd3    = ws3 + 256;                            // 256
    int* deg      = (int*)(wd3 + 256);                    // N
    int* cursor   = deg + N;                              // N (adjacent: 1 memset)
    int* off      = cursor + N;                           // N+4
    int* bsum     = off + N + 4;                          // 256
    int* csr_src  = bsum + 256;                           // Et

    const int B = 256;
    const int G = (N + 255) / 256;
    const int EB = (Et + B - 1) / B;

    // ---- CSR build (XCD-affine count/scatter) ----
    hipMemsetAsync(deg, 0, (size_t)2 * N * sizeof(int), stream);  // deg+cursor
    count_kernel<<<EB * 8, B, 0, stream>>>(dst, E, N, scale8, deg);
    scan_blocks<<<G, B, 0, stream>>>(deg, off, bsum, N);
    scan_bsums<<<1, B, 0, stream>>>(bsum, G, off + N);
    scan_add<<<G, B, 0, stream>>>(off, bsum, N);
    scatter_kernel<<<EB * 8, B, 0, stream>>>(src, dst, E, N, scale8,
                                             off, cursor, csr_src);

    // ---- all weight prep in one launch ----
    prep_all<<<133, B, 0, stream>>>(W1, a1s, a1d, ws1, wd1,
                                    W2, a2s, a2d, Wb2, ws2, wd2,
                                    W3, a3s, a3d, Wb3, ws3, wd3);

    int nwave_blocks = (N * 64 + B - 1) / B;   // wave per node
    int ngemm_blocks = (N + 63) / 64;          // 64 nodes per block

    // ---- Layer 1 (input-space aggregation over 3-dim x) ----
    logits1_kernel<<<(N + B - 1) / B, B, 0, stream>>>(
        x, ws1, wd1, (float4*)asrc, (float4*)adst, N);
    fused1_kernel<<<(N + B - 1) / B, B, 0, stream>>>(
        off, csr_src, x, (const float4*)asrc, (const float4*)adst,
        (float4*)zl, N);
    epi1_kernel<<<nwave_blocks, B, 0, stream>>>(
        (const float4*)zl, W1, b1, (const float4*)ws2, (const float4*)wd2,
        (float4*)asrc, (float4*)adst, bufA, xpA, N);

    // ---- Layer 2 (gemm epilogue folds layer-3 logits) ----
    agg_kernel<<<nwave_blocks, B, 0, stream>>>(
        off, csr_src, xpA, (const float4*)asrc, (const float4*)adst,
        (uint2*)zb, N);
    gemm_mfma<<<ngemm_blocks, B, 0, stream>>>(
        zb, Wb2, b2, bufA, (const float4*)ws3, (const float4*)wd3,
        (float4*)asrc, (float4*)adst,
        nullptr, nullptr, bufB, xpB, nullptr, N);

    // ---- Layer 3 (+ fused final linear) ----
    agg_kernel<<<nwave_blocks, B, 0, stream>>>(
        off, csr_src, xpB, (const float4*)asrc, (const float4*)adst,
        (uint2*)zb, N);
    gemm_mfma<<<ngemm_blocks, B, 0, stream>>>(
        zb, Wb3, b3, bufB, nullptr, nullptr, nullptr, nullptr,
        lin_w, lin_b, nullptr, nullptr, (float*)d_out, N);
}